// Round 1
// baseline (1201.234 us; speedup 1.0000x reference)
//
#include <hip/hip_runtime.h>
#include <cmath>

#define NB 4
#define NH 16
#define SD 64
#define SEQ 1024
#define ILEN 128
#define HIDDIM 1024

// ---------------------------------------------------------------------------
// Projection GEMM: out = X @ W + b, written as [B,H,T,D]
// z: 0=q 1=k 2=v (X=hidden, T=1024), 3=ik 4=iv (X=instruct, T=128)
// grid (16, 64, 5), block 256
// ---------------------------------------------------------------------------
__global__ __launch_bounds__(256) void proj_kernel(
    const float* __restrict__ hidden, const float* __restrict__ instruct,
    const float* __restrict__ Wq, const float* __restrict__ bq,
    const float* __restrict__ Wk, const float* __restrict__ bk,
    const float* __restrict__ Wv, const float* __restrict__ bv,
    float* __restrict__ qo, float* __restrict__ ko, float* __restrict__ vo,
    float* __restrict__ iko, float* __restrict__ ivo)
{
    const int z = blockIdx.z;
    const float* X; const float* W; const float* bias; float* out; int T;
    switch (z) {
      case 0: X=hidden;   W=Wq; bias=bq; out=qo;  T=SEQ;  break;
      case 1: X=hidden;   W=Wk; bias=bk; out=ko;  T=SEQ;  break;
      case 2: X=hidden;   W=Wv; bias=bv; out=vo;  T=SEQ;  break;
      case 3: X=instruct; W=Wk; bias=bk; out=iko; T=ILEN; break;
      default:X=instruct; W=Wv; bias=bv; out=ivo; T=ILEN; break;
    }
    const int M = NB * T;
    const int m0 = blockIdx.y * 64;
    if (m0 >= M) return;
    const int n0 = blockIdx.x * 64;

    __shared__ float As[16][68];   // [k][m], padded row stride 68 (16B aligned)
    __shared__ float Bs[16][64];   // [k][n]

    const int tid = threadIdx.x;
    const int ty = tid >> 4, tx = tid & 15;

    float acc[4][4];
    #pragma unroll
    for (int i=0;i<4;i++)
      #pragma unroll
      for (int j=0;j<4;j++) acc[i][j]=0.f;

    const int arow = tid >> 2;           // 0..63
    const int acol = (tid & 3) * 4;      // 0,4,8,12
    const int brow = tid >> 4;           // 0..15
    const int bcol = (tid & 15) * 4;     // 0..60

    for (int k0 = 0; k0 < HIDDIM; k0 += 16) {
        const float4 a = *(const float4*)&X[(size_t)(m0+arow)*HIDDIM + k0 + acol];
        const float4 w = *(const float4*)&W[(size_t)(k0+brow)*HIDDIM + n0 + bcol];
        __syncthreads();
        As[acol+0][arow]=a.x; As[acol+1][arow]=a.y;
        As[acol+2][arow]=a.z; As[acol+3][arow]=a.w;
        *(float4*)&Bs[brow][bcol] = w;
        __syncthreads();
        #pragma unroll
        for (int kk=0;kk<16;kk++) {
            const float4 av = *(const float4*)&As[kk][4*ty];
            const float4 bb = *(const float4*)&Bs[kk][4*tx];
            const float ar[4]={av.x,av.y,av.z,av.w};
            const float br[4]={bb.x,bb.y,bb.z,bb.w};
            #pragma unroll
            for (int i=0;i<4;i++)
              #pragma unroll
              for (int j=0;j<4;j++)
                acc[i][j] = fmaf(ar[i], br[j], acc[i][j]);
        }
    }

    const int h = n0 >> 6;
    #pragma unroll
    for (int i=0;i<4;i++) {
        const int m = m0 + 4*ty + i;
        const int bidx = (T==SEQ) ? (m >> 10) : (m >> 7);
        const int t = m & (T-1);
        float4 r;
        r.x = acc[i][0] + bias[n0+4*tx+0];
        r.y = acc[i][1] + bias[n0+4*tx+1];
        r.z = acc[i][2] + bias[n0+4*tx+2];
        r.w = acc[i][3] + bias[n0+4*tx+3];
        *(float4*)&out[(((size_t)bidx*NH + h)*T + t)*SD + 4*tx] = r;
    }
}

// ---------------------------------------------------------------------------
// Flash-style attention with relative-position band + gated instruct attn.
// One block per (b, h, 64-row q tile). block 256 = 16x16 threads.
// Each thread: scores for 4 rows x 2 cols; output acc 4 rows x 4 d-cols.
// grid (16, 16, 4)
// ---------------------------------------------------------------------------
__global__ __launch_bounds__(256) void attn_kernel(
    const float* __restrict__ qg, const float* __restrict__ kg, const float* __restrict__ vg,
    const float* __restrict__ ikg, const float* __restrict__ ivg,
    const float* __restrict__ mask, const float* __restrict__ imask,
    const float* __restrict__ gate, const float* __restrict__ dist_emb,
    float* __restrict__ out)
{
    const int l0 = blockIdx.x * 64;
    const int h  = blockIdx.y;
    const int b  = blockIdx.z;
    const int tid = threadIdx.x;
    const int ty = tid >> 4, tx = tid & 15;

    __shared__ float qs[64][68];    // q tile [l][d]
    __shared__ float kvs[32][68];   // k tile, then v tile
    __shared__ float es[95][68];    // dist_emb band [li-ri+31][d]
    __shared__ float ps[64][33];    // probs tile [l][r]

    const float* qb  = qg  + (((size_t)b*NH + h)*SEQ + l0)*SD;
    const float* kb  = kg  + ((size_t)b*NH + h)*SEQ*SD;
    const float* vb  = vg  + ((size_t)b*NH + h)*SEQ*SD;
    const float* ikb = ikg + ((size_t)b*NH + h)*ILEN*SD;
    const float* ivb = ivg + ((size_t)b*NH + h)*ILEN*SD;

    {   // load Q tile
        const int row = tid >> 4, dq = (tid & 15)*4;
        #pragma unroll
        for (int rep=0; rep<4; rep++)
            *(float4*)&qs[row+16*rep][dq] = *(const float4*)&qb[(size_t)(row+16*rep)*SD + dq];
    }

    float o1[4][4], o2[4][4], m1[4], l1[4], m2[4], l2[4];
    #pragma unroll
    for (int i=0;i<4;i++){
        m1[i]=-INFINITY; l1[i]=0.f; m2[i]=-INFINITY; l2[i]=0.f;
        #pragma unroll
        for (int j=0;j<4;j++){o1[i][j]=0.f;o2[i][j]=0.f;}
    }

    // es row for pair (i,j) is ebase + (i-j+1); ebase in [0,90]
    const int ebase = 4*ty - 2*tx + 30;

    // ---------------- main attention over S keys ----------------
    for (int r0=0; r0<SEQ; r0+=32) {
        __syncthreads();
        {   // K tile + E band
            const int row = tid >> 4, dq=(tid&15)*4;
            #pragma unroll
            for (int rep=0;rep<2;rep++)
                *(float4*)&kvs[row+16*rep][dq] = *(const float4*)&kb[(size_t)(r0+row+16*rep)*SD + dq];
            const int jb = l0 - r0 + 992;   // = (l0 - r0 - 31) + 1023, always in [0, 2046-94]
            for (int idx=tid; idx<95*16; idx+=256) {
                const int r2 = idx >> 4, d2=(idx&15)*4;
                *(float4*)&es[r2][d2] = *(const float4*)&dist_emb[(size_t)(jb+r2)*SD + d2];
            }
        }
        __syncthreads();

        float s[4][2];
        #pragma unroll
        for (int i=0;i<4;i++){s[i][0]=0.f; s[i][1]=0.f;}
        #pragma unroll 2
        for (int dq=0; dq<SD; dq+=4) {
            float4 qv[4], kv[2], ev[5];
            #pragma unroll
            for (int i=0;i<4;i++) qv[i]=*(const float4*)&qs[4*ty+i][dq];
            #pragma unroll
            for (int j=0;j<2;j++) kv[j]=*(const float4*)&kvs[2*tx+j][dq];
            #pragma unroll
            for (int m=0;m<5;m++) ev[m]=*(const float4*)&es[ebase+m][dq];
            #pragma unroll
            for (int i=0;i<4;i++)
              #pragma unroll
              for (int j=0;j<2;j++) {
                const float4 e = ev[i-j+1];
                const float* qp=(const float*)&qv[i];
                const float* kp=(const float*)&kv[j];
                const float* ep=(const float*)&e;
                float a=s[i][j];
                #pragma unroll
                for (int c=0;c<4;c++)
                    a += qp[c]*kp[c] + (qp[c]+kp[c])*ep[c];  // qk + (q+k)·e
                s[i][j]=a;
            }
        }

        // online softmax update (rows = 4*ty+i, reduce across 16 tx lanes)
        #pragma unroll
        for (int i=0;i<4;i++) {
            const float sv0 = s[i][0]*0.125f + mask[b*SEQ + r0 + 2*tx+0];
            const float sv1 = s[i][1]*0.125f + mask[b*SEQ + r0 + 2*tx+1];
            float mx = fmaxf(sv0,sv1);
            #pragma unroll
            for (int off=1; off<16; off<<=1) mx = fmaxf(mx, __shfl_xor(mx, off));
            const float mnew = fmaxf(m1[i], mx);
            const float alpha = __expf(m1[i]-mnew);
            m1[i]=mnew;
            const float p0=__expf(sv0-mnew), p1=__expf(sv1-mnew);
            float rs = p0+p1;
            #pragma unroll
            for (int off=1; off<16; off<<=1) rs += __shfl_xor(rs, off);
            l1[i] = l1[i]*alpha + rs;
            #pragma unroll
            for (int jd=0;jd<4;jd++) o1[i][jd]*=alpha;
            ps[4*ty+i][2*tx+0]=p0; ps[4*ty+i][2*tx+1]=p1;
        }
        __syncthreads();
        {   // V tile (reuse kvs)
            const int row=tid>>4, dq=(tid&15)*4;
            #pragma unroll
            for (int rep=0;rep<2;rep++)
                *(float4*)&kvs[row+16*rep][dq] = *(const float4*)&vb[(size_t)(r0+row+16*rep)*SD + dq];
        }
        __syncthreads();
        #pragma unroll 4
        for (int r=0;r<32;r++) {
            const float4 vv = *(const float4*)&kvs[r][4*tx];
            float pr[4];
            #pragma unroll
            for (int i=0;i<4;i++) pr[i]=ps[4*ty+i][r];
            #pragma unroll
            for (int i=0;i<4;i++){
                o1[i][0]=fmaf(pr[i],vv.x,o1[i][0]);
                o1[i][1]=fmaf(pr[i],vv.y,o1[i][1]);
                o1[i][2]=fmaf(pr[i],vv.z,o1[i][2]);
                o1[i][3]=fmaf(pr[i],vv.w,o1[i][3]);
            }
        }
    }

    // ---------------- instruct attention over L keys ----------------
    for (int r0=0; r0<ILEN; r0+=32) {
        __syncthreads();
        {
            const int row=tid>>4, dq=(tid&15)*4;
            #pragma unroll
            for (int rep=0;rep<2;rep++)
                *(float4*)&kvs[row+16*rep][dq] = *(const float4*)&ikb[(size_t)(r0+row+16*rep)*SD + dq];
        }
        __syncthreads();
        float s[4][2];
        #pragma unroll
        for (int i=0;i<4;i++){s[i][0]=0.f; s[i][1]=0.f;}
        #pragma unroll 2
        for (int dq=0; dq<SD; dq+=4) {
            float4 qv[4], kv[2];
            #pragma unroll
            for (int i=0;i<4;i++) qv[i]=*(const float4*)&qs[4*ty+i][dq];
            #pragma unroll
            for (int j=0;j<2;j++) kv[j]=*(const float4*)&kvs[2*tx+j][dq];
            #pragma unroll
            for (int i=0;i<4;i++)
              #pragma unroll
              for (int j=0;j<2;j++) {
                const float* qp=(const float*)&qv[i];
                const float* kp=(const float*)&kv[j];
                float a=s[i][j];
                #pragma unroll
                for (int c=0;c<4;c++) a = fmaf(qp[c],kp[c],a);
                s[i][j]=a;
            }
        }
        #pragma unroll
        for (int i=0;i<4;i++) {
            const float sv0 = s[i][0]*0.125f + imask[b*ILEN + r0 + 2*tx+0];
            const float sv1 = s[i][1]*0.125f + imask[b*ILEN + r0 + 2*tx+1];
            float mx = fmaxf(sv0,sv1);
            #pragma unroll
            for (int off=1; off<16; off<<=1) mx = fmaxf(mx, __shfl_xor(mx, off));
            const float mnew = fmaxf(m2[i], mx);
            const float alpha = __expf(m2[i]-mnew);
            m2[i]=mnew;
            const float p0=__expf(sv0-mnew), p1=__expf(sv1-mnew);
            float rs = p0+p1;
            #pragma unroll
            for (int off=1; off<16; off<<=1) rs += __shfl_xor(rs, off);
            l2[i] = l2[i]*alpha + rs;
            #pragma unroll
            for (int jd=0;jd<4;jd++) o2[i][jd]*=alpha;
            ps[4*ty+i][2*tx+0]=p0; ps[4*ty+i][2*tx+1]=p1;
        }
        __syncthreads();
        {
            const int row=tid>>4, dq=(tid&15)*4;
            #pragma unroll
            for (int rep=0;rep<2;rep++)
                *(float4*)&kvs[row+16*rep][dq] = *(const float4*)&ivb[(size_t)(r0+row+16*rep)*SD + dq];
        }
        __syncthreads();
        #pragma unroll 4
        for (int r=0;r<32;r++) {
            const float4 vv = *(const float4*)&kvs[r][4*tx];
            float pr[4];
            #pragma unroll
            for (int i=0;i<4;i++) pr[i]=ps[4*ty+i][r];
            #pragma unroll
            for (int i=0;i<4;i++){
                o2[i][0]=fmaf(pr[i],vv.x,o2[i][0]);
                o2[i][1]=fmaf(pr[i],vv.y,o2[i][1]);
                o2[i][2]=fmaf(pr[i],vv.z,o2[i][2]);
                o2[i][3]=fmaf(pr[i],vv.w,o2[i][3]);
            }
        }
    }

    // ---------------- epilogue: combine + transpose to [B,S,H,D] ----------------
    const float tg = tanhf(gate[h]);
    #pragma unroll
    for (int i=0;i<4;i++) {
        const int l = l0 + 4*ty + i;
        const float inv1 = 1.f/l1[i], inv2 = 1.f/l2[i];
        float4 r;
        r.x = o1[i][0]*inv1 + tg*(o2[i][0]*inv2);
        r.y = o1[i][1]*inv1 + tg*(o2[i][1]*inv2);
        r.z = o1[i][2]*inv1 + tg*(o2[i][2]*inv2);
        r.w = o1[i][3]*inv1 + tg*(o2[i][3]*inv2);
        *(float4*)&out[(((size_t)b*SEQ + l)*NH + h)*SD + 4*tx] = r;
    }
}

extern "C" void kernel_launch(void* const* d_in, const int* in_sizes, int n_in,
                              void* d_out, int out_size, void* d_ws, size_t ws_size,
                              hipStream_t stream) {
    const float* hidden  = (const float*)d_in[0];
    const float* mask    = (const float*)d_in[1];
    const float* ihidden = (const float*)d_in[2];
    const float* imask   = (const float*)d_in[3];
    const float* Wq = (const float*)d_in[4];
    const float* bq = (const float*)d_in[5];
    const float* Wk = (const float*)d_in[6];
    const float* bk = (const float*)d_in[7];
    const float* Wv = (const float*)d_in[8];
    const float* bv = (const float*)d_in[9];
    const float* gate = (const float*)d_in[10];
    const float* dist = (const float*)d_in[11];
    float* out = (float*)d_out;

    float* ws = (float*)d_ws;
    const size_t big = (size_t)NB*NH*SEQ*SD;    // 4M floats
    const size_t sml = (size_t)NB*NH*ILEN*SD;   // 512K floats
    float* qw  = ws;
    float* kw  = qw + big;
    float* vw  = kw + big;
    float* ikw = vw + big;
    float* ivw = ikw + sml;
    // total ws use: (3*4M + 2*512K) * 4B = 52 MB

    dim3 g1(16, 64, 5), blk(256);
    proj_kernel<<<g1, blk, 0, stream>>>(hidden, ihidden, Wq,bq, Wk,bk, Wv,bv,
                                        qw, kw, vw, ikw, ivw);
    dim3 g2(SEQ/64, NH, NB);
    attn_kernel<<<g2, blk, 0, stream>>>(qw, kw, vw, ikw, ivw,
                                        mask, imask, gate, dist, out);
}

// Round 2
// 308.006 us; speedup vs baseline: 3.9000x; 3.9000x over previous
//
#include <hip/hip_runtime.h>
#include <cmath>

#define NB 4
#define NH 16
#define SD 64
#define SEQ 1024
#define ILEN 128
#define HIDDIM 1024

#define N_HID (NB*SEQ*HIDDIM)     // 4194304
#define N_INS (NB*ILEN*HIDDIM)    // 524288
#define N_E_SRC (2047*SD)         // 131008
#define N_E   (2048*SD)           // 131072 (incl zero pad row)
#define N_W   (HIDDIM*HIDDIM)     // 1048576

typedef short bf8 __attribute__((ext_vector_type(8)));
typedef short bf4 __attribute__((ext_vector_type(4)));
typedef float f4  __attribute__((ext_vector_type(4)));

#define MFMA(a,b,c) __builtin_amdgcn_mfma_f32_16x16x32_bf16(a,b,c,0,0,0)

__device__ __forceinline__ float bf2f(short s) {
    unsigned u = ((unsigned)(unsigned short)s) << 16;
    return __uint_as_float(u);
}
__device__ __forceinline__ short f2bf(float x) {
    unsigned u = __float_as_uint(x);
    u = (u + 0x7FFFu + ((u >> 16) & 1u)) >> 16;
    return (short)u;
}

// ---------------------------------------------------------------------------
// Cast fp32 -> bf16: hidden, instruct, dist_emb (+1 zero pad row for E)
// ---------------------------------------------------------------------------
__global__ __launch_bounds__(256) void cast_flat(
    const float* __restrict__ hid, const float* __restrict__ ins,
    const float* __restrict__ E, short* __restrict__ ws)
{
    int i = (blockIdx.x * 256 + threadIdx.x) * 4;
    short* dhid = ws;
    short* dins = ws + N_HID;
    short* dE   = ws + N_HID + N_INS;
    if (i < N_HID) {
        float4 v = *(const float4*)&hid[i];
        bf4 o; o[0]=f2bf(v.x); o[1]=f2bf(v.y); o[2]=f2bf(v.z); o[3]=f2bf(v.w);
        *(bf4*)&dhid[i] = o;
    } else if (i < N_HID + N_INS) {
        int j = i - N_HID;
        float4 v = *(const float4*)&ins[j];
        bf4 o; o[0]=f2bf(v.x); o[1]=f2bf(v.y); o[2]=f2bf(v.z); o[3]=f2bf(v.w);
        *(bf4*)&dins[j] = o;
    } else {
        int j = i - N_HID - N_INS;
        if (j < N_E) {
            bf4 o;
            if (j < N_E_SRC) {
                float4 v = *(const float4*)&E[j];
                o[0]=f2bf(v.x); o[1]=f2bf(v.y); o[2]=f2bf(v.z); o[3]=f2bf(v.w);
            } else {
                o[0]=0; o[1]=0; o[2]=0; o[3]=0;
            }
            *(bf4*)&dE[j] = o;
        }
    }
}

// ---------------------------------------------------------------------------
// Cast + transpose W -> WT bf16 (WT[n][k] = W[k][n]); grid (16,16,3)
// ---------------------------------------------------------------------------
__global__ __launch_bounds__(256) void cast_wt(
    const float* __restrict__ Wq, const float* __restrict__ Wk,
    const float* __restrict__ Wv, short* __restrict__ dstbase)
{
    const float* W = (blockIdx.z==0) ? Wq : (blockIdx.z==1) ? Wk : Wv;
    short* dst = dstbase + (size_t)blockIdx.z * N_W;
    const int k0 = blockIdx.y*64, n0 = blockIdx.x*64;
    __shared__ float st[64][65];
    const int tid = threadIdx.x;
    #pragma unroll
    for (int rep=0; rep<4; rep++) {
        int u = tid + rep*256;
        int row = u >> 4, col = (u & 15) * 4;
        float4 v = *(const float4*)&W[(size_t)(k0+row)*HIDDIM + n0 + col];
        st[row][col+0]=v.x; st[row][col+1]=v.y; st[row][col+2]=v.z; st[row][col+3]=v.w;
    }
    __syncthreads();
    #pragma unroll
    for (int rep=0; rep<4; rep++) {
        int u = tid + rep*256;
        int nrow = u >> 4, kc = (u & 15) * 4;
        bf4 o;
        #pragma unroll
        for (int j=0;j<4;j++) o[j] = f2bf(st[kc+j][nrow]);
        *(bf4*)&dst[(size_t)(n0+nrow)*HIDDIM + k0 + kc] = o;
    }
}

// ---------------------------------------------------------------------------
// Projection GEMM (bf16 MFMA): out = X @ W + b
// z: 0=q 1=k 2=vT 3=ik 4=ivT ; grid (16, 64, 5), block 256 (4 waves)
// q/k/ik stored [B,H,T,D] bf16; vT/ivT stored [B,H,D,T] bf16
// ---------------------------------------------------------------------------
__global__ __launch_bounds__(256) void proj_mfma(
    const short* __restrict__ hidb, const short* __restrict__ insb,
    const short* __restrict__ WqT, const short* __restrict__ WkT, const short* __restrict__ WvT,
    const float* __restrict__ bq, const float* __restrict__ bk, const float* __restrict__ bv,
    short* __restrict__ qo, short* __restrict__ ko, short* __restrict__ vTo,
    short* __restrict__ iko, short* __restrict__ ivTo)
{
    const int z = blockIdx.z;
    const short* X; const short* WT; const float* bias; short* outp;
    int T, tsh, mode;
    switch (z) {
      case 0: X=hidb; WT=WqT; bias=bq; outp=qo;   T=SEQ;  tsh=10; mode=0; break;
      case 1: X=hidb; WT=WkT; bias=bk; outp=ko;   T=SEQ;  tsh=10; mode=0; break;
      case 2: X=hidb; WT=WvT; bias=bv; outp=vTo;  T=SEQ;  tsh=10; mode=1; break;
      case 3: X=insb; WT=WkT; bias=bk; outp=iko;  T=ILEN; tsh=7;  mode=0; break;
      default:X=insb; WT=WvT; bias=bv; outp=ivTo; T=ILEN; tsh=7;  mode=1; break;
    }
    const int M = NB * T;
    const int m0 = blockIdx.y * 64;
    if (m0 >= M) return;
    const int n0 = blockIdx.x * 64;
    const int h  = blockIdx.x;

    __shared__ short Xs[64*72];
    __shared__ short Ws[64*72];

    const int tid = threadIdx.x, w = tid>>6, lane = tid&63, quad = lane>>4, nl = lane&15;

    f4 acc[4];
    #pragma unroll
    for (int t=0;t<4;t++) { acc[t][0]=0.f; acc[t][1]=0.f; acc[t][2]=0.f; acc[t][3]=0.f; }

    for (int k0=0; k0<HIDDIM; k0+=64) {
        __syncthreads();
        #pragma unroll
        for (int rep=0; rep<2; rep++) {
            int u = tid + rep*256;
            int row = u >> 3, ch = u & 7;
            *(uint4*)&Xs[row*72 + ch*8] = *(const uint4*)&X[(size_t)(m0+row)*HIDDIM + k0 + ch*8];
            *(uint4*)&Ws[row*72 + ch*8] = *(const uint4*)&WT[(size_t)(n0+row)*HIDDIM + k0 + ch*8];
        }
        __syncthreads();
        #pragma unroll
        for (int s=0;s<2;s++) {
            bf8 a = *(const bf8*)&Xs[(16*w+nl)*72 + s*32 + quad*8];
            #pragma unroll
            for (int t=0;t<4;t++) {
                bf8 bb = *(const bf8*)&Ws[(16*t+nl)*72 + s*32 + quad*8];
                acc[t] = MFMA(a, bb, acc[t]);
            }
        }
    }

    const int mrow0 = m0 + 16*w + quad*4;
    #pragma unroll
    for (int t=0;t<4;t++) {
        const int d = 16*t + nl;
        const float bsv = bias[n0 + d];
        if (mode) {
            bf4 o;
            #pragma unroll
            for (int i=0;i<4;i++) o[i] = f2bf(acc[t][i] + bsv);
            const int m = mrow0;
            const int bb_ = m >> tsh;
            const int tt  = m & (T-1);
            *(bf4*)&outp[((size_t)(bb_*NH + h)*SD + d)*T + tt] = o;
        } else {
            #pragma unroll
            for (int i=0;i<4;i++) {
                const int m = mrow0 + i;
                const int bb_ = m >> tsh;
                const int tt  = m & (T-1);
                outp[((size_t)(bb_*NH + h)*T + tt)*SD + d] = f2bf(acc[t][i] + bsv);
            }
        }
    }
}

// ---------------------------------------------------------------------------
// Fused attention (bf16 MFMA): flash + relative-position band matmuls + gated
// instruct attention. One block per (b, h, 64 q-rows); BN=64 per iter.
// grid (16,16,4), block 256 (4 waves). ~81 KB LDS -> 2 blocks/CU.
// ---------------------------------------------------------------------------
__global__ __launch_bounds__(256,2) void attn_mfma(
    const short* __restrict__ qg, const short* __restrict__ kg, const short* __restrict__ vTg,
    const short* __restrict__ ikg, const short* __restrict__ ivTg,
    const float* __restrict__ mask, const float* __restrict__ imask,
    const float* __restrict__ gate, const short* __restrict__ Ebf,
    float* __restrict__ out)
{
    const int l0 = blockIdx.x * 64, h = blockIdx.y, b = blockIdx.z;
    const int tid = threadIdx.x, w = tid>>6, lane = tid&63, quad = lane>>4, nl = lane&15;

    __shared__ short qs [64*72];
    __shared__ short ksh[64*72];
    __shared__ short vts[64*72];
    __shared__ short es [128*72];
    __shared__ short qeT[128*68];
    __shared__ short keT[128*68];
    __shared__ float maskS[64];
    short* ps = qeT;   // alias: P tile [64][72] reuses qeT region

    const size_t bh = (size_t)(b*NH + h);
    const short* qbase   = qg   + (bh*SEQ + l0)*SD;
    const short* kbase   = kg   + bh*SEQ*SD;
    const short* vTbase  = vTg  + bh*SD*SEQ;
    const short* ikbase  = ikg  + bh*ILEN*SD;
    const short* ivTbase = ivTg + bh*SD*ILEN;

    // stage Q tile once
    #pragma unroll
    for (int rep=0; rep<2; rep++) {
        int u = tid + rep*256;
        int row = u >> 3, ch = u & 7;
        *(uint4*)&qs[row*72 + ch*8] = *(const uint4*)&qbase[(size_t)row*SD + ch*8];
    }

    f4 o1[4], o2[4];
    float m1[4], l1[4], m2[4], l2[4];
    #pragma unroll
    for (int t=0;t<4;t++) {
        o1[t][0]=0.f;o1[t][1]=0.f;o1[t][2]=0.f;o1[t][3]=0.f;
        o2[t][0]=0.f;o2[t][1]=0.f;o2[t][2]=0.f;o2[t][3]=0.f;
        m1[t]=-1e30f; l1[t]=0.f; m2[t]=-1e30f; l2[t]=0.f;
    }

    // ======================= main attention over S keys =====================
    for (int r0=0; r0<SEQ; r0+=64) {
        __syncthreads();
        #pragma unroll
        for (int rep=0; rep<2; rep++) {
            int u = tid + rep*256;
            int row = u >> 3, ch = u & 7;
            *(uint4*)&ksh[row*72 + ch*8] = *(const uint4*)&kbase[(size_t)(r0+row)*SD + ch*8];
            *(uint4*)&vts[row*72 + ch*8] = *(const uint4*)&vTbase[(size_t)row*SEQ + r0 + ch*8];
        }
        const int jb = l0 - r0 + 960;   // E row window base (incl +1023 offset)
        #pragma unroll
        for (int rep=0; rep<4; rep++) {
            int u = tid + rep*256;
            int row = u >> 3, ch = u & 7;
            *(uint4*)&es[row*72 + ch*8] = *(const uint4*)&Ebf[(size_t)(jb+row)*SD + ch*8];
        }
        if (tid < 64) maskS[tid] = mask[b*SEQ + r0 + tid];
        __syncthreads();

        bf8 aq[2], ak[2];
        #pragma unroll
        for (int s=0;s<2;s++) {
            aq[s] = *(const bf8*)&qs [(16*w+nl)*72 + s*32 + quad*8];
            ak[s] = *(const bf8*)&ksh[(16*w+nl)*72 + s*32 + quad*8];
        }
        // QK^T
        f4 sc[4];
        #pragma unroll
        for (int t=0;t<4;t++) { sc[t][0]=0.f; sc[t][1]=0.f; sc[t][2]=0.f; sc[t][3]=0.f; }
        #pragma unroll
        for (int t=0;t<4;t++)
            #pragma unroll
            for (int s=0;s<2;s++) {
                bf8 bk = *(const bf8*)&ksh[(16*t+nl)*72 + s*32 + quad*8];
                sc[t] = MFMA(aq[s], bk, sc[t]);
            }
        // band matmuls: Qe = Q @ E^T, Ke = K @ E^T  (shared E b-fragments)
        f4 qe[8], ke[8];
        #pragma unroll
        for (int tc=0;tc<8;tc++) {
            qe[tc][0]=0.f;qe[tc][1]=0.f;qe[tc][2]=0.f;qe[tc][3]=0.f;
            ke[tc][0]=0.f;ke[tc][1]=0.f;ke[tc][2]=0.f;ke[tc][3]=0.f;
        }
        #pragma unroll
        for (int tc=0;tc<8;tc++)
            #pragma unroll
            for (int s=0;s<2;s++) {
                bf8 be = *(const bf8*)&es[(16*tc+nl)*72 + s*32 + quad*8];
                qe[tc] = MFMA(aq[s], be, qe[tc]);
                ke[tc] = MFMA(ak[s], be, ke[tc]);
            }
        // store bands transposed (bf16): qeT[c][l], keT[c][r]
        #pragma unroll
        for (int tc=0;tc<8;tc++) {
            bf4 pq, pk;
            #pragma unroll
            for (int i=0;i<4;i++) { pq[i]=f2bf(qe[tc][i]); pk[i]=f2bf(ke[tc][i]); }
            const int c = 16*tc + nl;
            *(bf4*)&qeT[c*68 + 16*w + quad*4] = pq;
            *(bf4*)&keT[c*68 + 16*w + quad*4] = pk;
        }
        __syncthreads();

        // shear gather + online softmax
        float sval[4][4];   // [row i][col tile t]
        #pragma unroll
        for (int t=0;t<4;t++) {
            const int ri = 16*t + nl;
            const float mk = maskS[ri];
            #pragma unroll
            for (int i=0;i<4;i++) {
                const int li = 16*w + quad*4 + i;
                const int c = li - ri + 63;
                float add = bf2f(qeT[c*68 + li]) + bf2f(keT[c*68 + ri]);
                sval[i][t] = (sc[t][i] + add)*0.125f + mk;
            }
        }
        short pbf[4][4];
        #pragma unroll
        for (int i=0;i<4;i++) {
            float mx = fmaxf(fmaxf(sval[i][0],sval[i][1]), fmaxf(sval[i][2],sval[i][3]));
            #pragma unroll
            for (int off=1; off<16; off<<=1) mx = fmaxf(mx, __shfl_xor(mx, off));
            const float mn = fmaxf(m1[i], mx);
            const float alpha = __expf(m1[i]-mn);
            m1[i] = mn;
            float rs = 0.f;
            #pragma unroll
            for (int t=0;t<4;t++) {
                float p = __expf(sval[i][t]-mn);
                pbf[i][t] = f2bf(p);
                rs += p;
            }
            #pragma unroll
            for (int off=1; off<16; off<<=1) rs += __shfl_xor(rs, off);
            l1[i] = l1[i]*alpha + rs;
            #pragma unroll
            for (int t=0;t<4;t++) o1[t][i] *= alpha;
        }
        __syncthreads();   // all gathers done before P overwrites qeT
        #pragma unroll
        for (int i=0;i<4;i++) {
            const int li = 16*w + quad*4 + i;
            #pragma unroll
            for (int t=0;t<4;t++) ps[li*72 + 16*t + nl] = pbf[i][t];
        }
        __syncthreads();
        // PV
        #pragma unroll
        for (int s=0;s<2;s++) {
            bf8 ap = *(const bf8*)&ps[(16*w+nl)*72 + s*32 + quad*8];
            #pragma unroll
            for (int t=0;t<4;t++) {
                bf8 bv = *(const bf8*)&vts[(16*t+nl)*72 + s*32 + quad*8];
                o1[t] = MFMA(ap, bv, o1[t]);
            }
        }
    }

    // ==================== instruct attention over L keys ====================
    for (int r0=0; r0<ILEN; r0+=64) {
        __syncthreads();
        #pragma unroll
        for (int rep=0; rep<2; rep++) {
            int u = tid + rep*256;
            int row = u >> 3, ch = u & 7;
            *(uint4*)&ksh[row*72 + ch*8] = *(const uint4*)&ikbase[(size_t)(r0+row)*SD + ch*8];
            *(uint4*)&vts[row*72 + ch*8] = *(const uint4*)&ivTbase[(size_t)row*ILEN + r0 + ch*8];
        }
        if (tid < 64) maskS[tid] = imask[b*ILEN + r0 + tid];
        __syncthreads();

        bf8 aq[2];
        #pragma unroll
        for (int s=0;s<2;s++) aq[s] = *(const bf8*)&qs[(16*w+nl)*72 + s*32 + quad*8];
        f4 sc[4];
        #pragma unroll
        for (int t=0;t<4;t++) { sc[t][0]=0.f; sc[t][1]=0.f; sc[t][2]=0.f; sc[t][3]=0.f; }
        #pragma unroll
        for (int t=0;t<4;t++)
            #pragma unroll
            for (int s=0;s<2;s++) {
                bf8 bk = *(const bf8*)&ksh[(16*t+nl)*72 + s*32 + quad*8];
                sc[t] = MFMA(aq[s], bk, sc[t]);
            }
        float sval[4][4];
        #pragma unroll
        for (int t=0;t<4;t++) {
            const float mk = maskS[16*t + nl];
            #pragma unroll
            for (int i=0;i<4;i++) sval[i][t] = sc[t][i]*0.125f + mk;
        }
        short pbf[4][4];
        #pragma unroll
        for (int i=0;i<4;i++) {
            float mx = fmaxf(fmaxf(sval[i][0],sval[i][1]), fmaxf(sval[i][2],sval[i][3]));
            #pragma unroll
            for (int off=1; off<16; off<<=1) mx = fmaxf(mx, __shfl_xor(mx, off));
            const float mn = fmaxf(m2[i], mx);
            const float alpha = __expf(m2[i]-mn);
            m2[i] = mn;
            float rs = 0.f;
            #pragma unroll
            for (int t=0;t<4;t++) {
                float p = __expf(sval[i][t]-mn);
                pbf[i][t] = f2bf(p);
                rs += p;
            }
            #pragma unroll
            for (int off=1; off<16; off<<=1) rs += __shfl_xor(rs, off);
            l2[i] = l2[i]*alpha + rs;
            #pragma unroll
            for (int t=0;t<4;t++) o2[t][i] *= alpha;
        }
        // each wave reads only its own ps rows -> no cross-wave hazard here
        #pragma unroll
        for (int i=0;i<4;i++) {
            const int li = 16*w + quad*4 + i;
            #pragma unroll
            for (int t=0;t<4;t++) ps[li*72 + 16*t + nl] = pbf[i][t];
        }
        #pragma unroll
        for (int s=0;s<2;s++) {
            bf8 ap = *(const bf8*)&ps[(16*w+nl)*72 + s*32 + quad*8];
            #pragma unroll
            for (int t=0;t<4;t++) {
                bf8 bv = *(const bf8*)&vts[(16*t+nl)*72 + s*32 + quad*8];
                o2[t] = MFMA(ap, bv, o2[t]);
            }
        }
    }

    // ============================== epilogue ================================
    const float tg = tanhf(gate[h]);
    #pragma unroll
    for (int i=0;i<4;i++) {
        const int l = l0 + 16*w + quad*4 + i;
        const float inv1 = 1.0f/l1[i], inv2 = 1.0f/l2[i];
        #pragma unroll
        for (int t=0;t<4;t++) {
            const int d = 16*t + nl;
            out[((size_t)(b*SEQ + l)*NH + h)*SD + d] = o1[t][i]*inv1 + tg*(o2[t][i]*inv2);
        }
    }
}

extern "C" void kernel_launch(void* const* d_in, const int* in_sizes, int n_in,
                              void* d_out, int out_size, void* d_ws, size_t ws_size,
                              hipStream_t stream) {
    const float* hidden  = (const float*)d_in[0];
    const float* mask    = (const float*)d_in[1];
    const float* ihidden = (const float*)d_in[2];
    const float* imask   = (const float*)d_in[3];
    const float* Wq   = (const float*)d_in[4];
    const float* bq   = (const float*)d_in[5];
    const float* Wk   = (const float*)d_in[6];
    const float* bk   = (const float*)d_in[7];
    const float* Wv   = (const float*)d_in[8];
    const float* bv   = (const float*)d_in[9];
    const float* gate = (const float*)d_in[10];
    const float* dist = (const float*)d_in[11];
    float* out = (float*)d_out;

    short* ws = (short*)d_ws;
    const size_t OFF_INS = N_HID;
    const size_t OFF_E   = OFF_INS + N_INS;
    const size_t OFF_WT  = OFF_E + N_E;              // 3 transposed W's
    const size_t OFF_Q   = OFF_WT + 3*(size_t)N_W;
    const size_t OFF_K   = OFF_Q + N_HID;
    const size_t OFF_VT  = OFF_K + N_HID;
    const size_t OFF_IK  = OFF_VT + N_HID;
    const size_t OFF_IVT = OFF_IK + N_INS;
    // total ws: (OFF_IVT + N_INS) * 2B = 43.25 MB

    cast_flat<<<4736, 256, 0, stream>>>(hidden, ihidden, dist, ws);
    cast_wt<<<dim3(16,16,3), 256, 0, stream>>>(Wq, Wk, Wv, ws + OFF_WT);
    proj_mfma<<<dim3(16,64,5), 256, 0, stream>>>(
        ws, ws + OFF_INS,
        ws + OFF_WT, ws + OFF_WT + N_W, ws + OFF_WT + 2*(size_t)N_W,
        bq, bk, bv,
        ws + OFF_Q, ws + OFF_K, ws + OFF_VT, ws + OFF_IK, ws + OFF_IVT);
    attn_mfma<<<dim3(16,16,4), 256, 0, stream>>>(
        ws + OFF_Q, ws + OFF_K, ws + OFF_VT, ws + OFF_IK, ws + OFF_IVT,
        mask, imask, gate, ws + OFF_E, out);
}